// Round 18
// baseline (239.240 us; speedup 1.0000x reference)
//
#include <hip/hip_runtime.h>
#include <math.h>

#define NB 4
#define L 512
#define DN 128
#define DP 64
#define H 8
#define HD 32
#define NH (H*HD)        // 256
#define AGG (NH + H*DP)  // 768
#define JC 64
#define NCH (L/JC)       // 8

// static device scratch
__device__ float g_qT[(size_t)NB*H*L*HD];  // [n][h][i][d], q*0.125
__device__ float g_kT[(size_t)NB*H*L*HD];  // [n][h][j][d]
__device__ float g_v[NB*L*NH];             // [n][j][h*32+d]
__device__ float g_agg[NB*L*AGG];
__device__ float g_nl[(size_t)NB*H*L*L];   // 33.5MB [n][h][i][j]

// ---------------- K1: QKV projection (4 rows / block) ----------------
__global__ __launch_bounds__(256) void k_qkv(const float* __restrict__ x,
    const float* __restrict__ Wq, const float* __restrict__ Wk,
    const float* __restrict__ Wv)
{
    __shared__ float xs[4*DN];
    int t = threadIdx.x;
    int rowbase = blockIdx.x * 4;
    #pragma unroll
    for (int it = 0; it < 2; ++it) {
        int flat = it*256 + t;
        xs[flat] = x[(size_t)rowbase*DN + flat];
    }
    __syncthreads();
    float aq[4], ak[4], av[4];
    #pragma unroll
    for (int r = 0; r < 4; ++r) { aq[r]=0.f; ak[r]=0.f; av[r]=0.f; }
    for (int d = 0; d < DN; ++d) {
        float wq = Wq[d*NH + t];
        float wk = Wk[d*NH + t];
        float wv = Wv[d*NH + t];
        #pragma unroll
        for (int r = 0; r < 4; ++r) {
            float xv = xs[r*DN + d];
            aq[r] = fmaf(xv, wq, aq[r]);
            ak[r] = fmaf(xv, wk, ak[r]);
            av[r] = fmaf(xv, wv, av[r]);
        }
    }
    int n2 = rowbase >> 9;
    int i0 = rowbase & 511;
    int h = t >> 5, d = t & 31;
    #pragma unroll
    for (int r = 0; r < 4; ++r) {
        // q/k transposed per-head rows ([n][h][i][d]); fold (1/sqrt32)*sqrt(.5)=0.125 into q
        size_t base = ((size_t)(n2*H + h)*L + i0 + r)*HD + d;
        g_qT[base] = aq[r] * 0.125f;
        g_kT[base] = ak[r];
        g_v[(size_t)(rowbase+r)*NH + t] = av[r];
    }
}

// ---------------- K1.5: node logits GEMM: nl[n,h,i,j] = q[i]·k[j] ----------------
__global__ __launch_bounds__(256) void k_qk()
{
    __shared__ __align__(16) float qs[16*36];
    int t = threadIdx.x;
    int bid = blockIdx.x;            // n*256 + h*32 + itile
    int n = bid >> 8;
    int h = (bid >> 5) & 7;
    int i0 = (bid & 31) << 4;
    const float* qTb = g_qT + (size_t)((n*H + h)*L + i0)*HD;
    if (t < 128) {
        int row = t >> 3, c4 = (t & 7) << 2;
        float4 qv = *(const float4*)(qTb + row*HD + c4);
        *(float4*)&qs[row*36 + c4] = qv;
    }
    __syncthreads();
    const float* kTb = g_kT + (size_t)(n*H + h)*L*HD;
    for (int jc = 0; jc < L; jc += 256) {
        int j = jc + t;
        float4 kr[8];
        const float4* kb = (const float4*)(kTb + (size_t)j*HD);
        #pragma unroll
        for (int c4 = 0; c4 < 8; ++c4) kr[c4] = kb[c4];
        float* outb = g_nl + (size_t)((n*H + h)*L + i0)*L + j;
        #pragma unroll 4
        for (int i = 0; i < 16; ++i) {
            float a0 = 0.f, a1 = 0.f;
            #pragma unroll
            for (int c4 = 0; c4 < 8; c4 += 2) {
                float4 q0 = *(const float4*)&qs[i*36 + c4*4];
                float4 q1 = *(const float4*)&qs[i*36 + c4*4 + 4];
                a0 = fmaf(q0.x, kr[c4].x,   fmaf(q0.y, kr[c4].y,   a0));
                a0 = fmaf(q0.z, kr[c4].z,   fmaf(q0.w, kr[c4].w,   a0));
                a1 = fmaf(q1.x, kr[c4+1].x, fmaf(q1.y, kr[c4+1].y, a1));
                a1 = fmaf(q1.z, kr[c4+1].z, fmaf(q1.w, kr[c4+1].w, a1));
            }
            outb[(size_t)i*L] = a0 + a1;
        }
    }
}

// ---------------- K2: wave-private flash attention, NO z LDS staging ----------
// r15 skeleton with the z LDS round-trip removed (guide m169: staging L2-fit
// data is pure overhead). Phase D re-reads z[j][lane] from global: 256B
// coalesced per j, L2-hot (fetched by ZLOAD <=2 chunks earlier).

#define LOGITS(BUF, NLARR)                                                     \
  { _Pragma("unroll")                                                          \
    for (int it2 = 0; it2 < 4; ++it2) {                                        \
      float4 zv = zR[it2];                                                     \
      float p0 = fmaf(zv.x,wA0.x, fmaf(zv.y,wA1.x, fmaf(zv.z,wA2.x, zv.w*wA3.x))); \
      float p1 = fmaf(zv.x,wA0.y, fmaf(zv.y,wA1.y, fmaf(zv.z,wA2.y, zv.w*wA3.y))); \
      float p2 = fmaf(zv.x,wA0.z, fmaf(zv.y,wA1.z, fmaf(zv.z,wA2.z, zv.w*wA3.z))); \
      float p3 = fmaf(zv.x,wA0.w, fmaf(zv.y,wA1.w, fmaf(zv.z,wA2.w, zv.w*wA3.w))); \
      float p4 = fmaf(zv.x,wB0.x, fmaf(zv.y,wB1.x, fmaf(zv.z,wB2.x, zv.w*wB3.x))); \
      float p5 = fmaf(zv.x,wB0.y, fmaf(zv.y,wB1.y, fmaf(zv.z,wB2.y, zv.w*wB3.y))); \
      float p6 = fmaf(zv.x,wB0.z, fmaf(zv.y,wB1.z, fmaf(zv.z,wB2.z, zv.w*wB3.z))); \
      float p7 = fmaf(zv.x,wB0.w, fmaf(zv.y,wB1.w, fmaf(zv.z,wB2.w, zv.w*wB3.w))); \
      bool s8 = (lane & 8) != 0;                                               \
      float k0 = s8 ? p4 : p0, d0 = s8 ? p0 : p4;                              \
      float k1 = s8 ? p5 : p1, d1 = s8 ? p1 : p5;                              \
      float k2 = s8 ? p6 : p2, d2 = s8 ? p2 : p6;                              \
      float k3 = s8 ? p7 : p3, d3 = s8 ? p3 : p7;                              \
      k0 += __shfl_xor(d0, 8); k1 += __shfl_xor(d1, 8);                        \
      k2 += __shfl_xor(d2, 8); k3 += __shfl_xor(d3, 8);                        \
      bool s4 = (lane & 4) != 0;                                               \
      float m0 = s4 ? k2 : k0, e0 = s4 ? k0 : k2;                              \
      float m1 = s4 ? k3 : k1, e1 = s4 ? k1 : k3;                              \
      m0 += __shfl_xor(e0, 4); m1 += __shfl_xor(e1, 4);                        \
      bool s2b = (lane & 2) != 0;                                              \
      float r0 = s2b ? m1 : m0, r1 = s2b ? m0 : m1;                            \
      r0 += __shfl_xor(r1, 2);                                                 \
      r0 += __shfl_xor(r0, 1);                                                 \
      float e = __expf(r0 + NLARR[it2]);                                       \
      if (!(lane & 1)) { s_part += e; lcw[BUF][wv][it2*4 + g][h] = e; }        \
    } }

#define ZLOAD(cc)                                                              \
  { const float4* sp = (const float4*)(zrow + (size_t)(cc)*JC*DP);             \
    zR[0]=sp[t]; zR[1]=sp[256+t]; zR[2]=sp[512+t]; zR[3]=sp[768+t]; }

#define NLOAD(cc, ARR)                                                         \
  { _Pragma("unroll")                                                          \
    for (int q2 = 0; q2 < 4; ++q2) ARR[q2] = nlb[(cc)*64 + q2*16]; }

#define PHASED(cc)                                                             \
  { const float* zch = zrow + (size_t)(cc)*JC*DP + lane;                       \
    const float* vb = g_v + (size_t)(n*L + (size_t)(cc)*JC)*NH + lane;         \
    _Pragma("unroll 4")                                                        \
    for (int jl = 0; jl < 16; ++jl) {                                          \
      int j = ((jl>>2)<<4) + 4*wv + (jl&3);                                    \
      float4 aL = *(const float4*)&lcw[(cc)&1][wv][jl][0];                     \
      float4 aH = *(const float4*)&lcw[(cc)&1][wv][jl][4];                     \
      float zv = zch[(size_t)j*DP];                                            \
      const float* vr = vb + (size_t)j*NH;                                     \
      float v0 = vr[0], v1 = vr[64], v2 = vr[128], v3 = vr[192];               \
      accP[0] = fmaf(aL.x, zv, accP[0]);                                       \
      accP[1] = fmaf(aL.y, zv, accP[1]);                                       \
      accP[2] = fmaf(aL.z, zv, accP[2]);                                       \
      accP[3] = fmaf(aL.w, zv, accP[3]);                                       \
      accP[4] = fmaf(aH.x, zv, accP[4]);                                       \
      accP[5] = fmaf(aH.y, zv, accP[5]);                                       \
      accP[6] = fmaf(aH.z, zv, accP[6]);                                       \
      accP[7] = fmaf(aH.w, zv, accP[7]);                                       \
      float a0 = hi ? aL.y : aL.x;                                             \
      float a1 = hi ? aL.w : aL.z;                                             \
      float a2 = hi ? aH.y : aH.x;                                             \
      float a3 = hi ? aH.w : aH.z;                                             \
      accN4[0] = fmaf(a0, v0, accN4[0]);                                       \
      accN4[1] = fmaf(a1, v1, accN4[1]);                                       \
      accN4[2] = fmaf(a2, v2, accN4[2]);                                       \
      accN4[3] = fmaf(a3, v3, accN4[3]);                                       \
    } }

#define AITER(c, USE, LOADINTO)                                                \
  { if ((c)+1 < NCH) { LOGITS(((c)+1)&1, USE) }                                \
    if ((c)+2 < NCH) { ZLOAD((c)+2) NLOAD((c)+2, LOADINTO) }                   \
    PHASED(c) }

__global__ __launch_bounds__(256) void k_attn(const float* __restrict__ z,
    const float* __restrict__ Wp)
{
    __shared__ __align__(16) float lcw[2][4][16][8]; // 4 KB alpha, wave-private
    __shared__ __align__(16) float scr[3200];        // 12.8 KB final-combine scratch

    int t = threadIdx.x;
    int lane = t & 63;
    int wv = t >> 6;
    int row = blockIdx.x;            // n*L + i
    int n = row >> 9;
    int i = row & 511;
    const float* zrow = z + (size_t)row * (L*DP);

    int g = lane >> 4;               // j-group within wave (0..3)
    int b = lane & 15;               // position in group = p-slice index
    int h = (lane & 14) >> 1;        // head this thread reduces to
    bool hi = (lane >= 32);

    // Wp slice in registers: rows p=4b..4b+3, heads 0-3 (wA*) and 4-7 (wB*)
    const float SQ = 0.70710678118654752f;
    float4 wA0, wA1, wA2, wA3, wB0, wB1, wB2, wB3;
    {
        const float4* w0 = (const float4*)(Wp + (4*b + 0)*H);
        const float4* w1 = (const float4*)(Wp + (4*b + 1)*H);
        const float4* w2 = (const float4*)(Wp + (4*b + 2)*H);
        const float4* w3 = (const float4*)(Wp + (4*b + 3)*H);
        wA0 = w0[0]; wB0 = w0[1]; wA1 = w1[0]; wB1 = w1[1];
        wA2 = w2[0]; wB2 = w2[1]; wA3 = w3[0]; wB3 = w3[1];
        wA0.x*=SQ; wA0.y*=SQ; wA0.z*=SQ; wA0.w*=SQ;
        wA1.x*=SQ; wA1.y*=SQ; wA1.z*=SQ; wA1.w*=SQ;
        wA2.x*=SQ; wA2.y*=SQ; wA2.z*=SQ; wA2.w*=SQ;
        wA3.x*=SQ; wA3.y*=SQ; wA3.z*=SQ; wA3.w*=SQ;
        wB0.x*=SQ; wB0.y*=SQ; wB0.z*=SQ; wB0.w*=SQ;
        wB1.x*=SQ; wB1.y*=SQ; wB1.z*=SQ; wB1.w*=SQ;
        wB2.x*=SQ; wB2.y*=SQ; wB2.z*=SQ; wB2.w*=SQ;
        wB3.x*=SQ; wB3.y*=SQ; wB3.z*=SQ; wB3.w*=SQ;
    }

    // nl pointer for (head h, query i), j-offset 4wv+g; nlb[c*64 + 16*it2]
    const float* nlb = g_nl + ((size_t)((n*H + h)*L + i))*L + 4*wv + g;

    float accP[8] = {0.f,0.f,0.f,0.f,0.f,0.f,0.f,0.f};
    float accN4[4] = {0.f,0.f,0.f,0.f};
    float s_part = 0.f;
    float4 zR[4];
    float nlC[4], nlN[4];

    // prologue: chunk0 regs -> logits(0); zR <- chunk1
    ZLOAD(0) NLOAD(0, nlC)
    LOGITS(0, nlC)
    ZLOAD(1) NLOAD(1, nlN)

    AITER(0, nlN, nlC)
    AITER(1, nlC, nlN)
    AITER(2, nlN, nlC)
    AITER(3, nlC, nlN)
    AITER(4, nlN, nlC)
    AITER(5, nlC, nlN)
    AITER(6, nlN, nlC)
    AITER(7, nlC, nlN)

    // ---- cross-wave combine (only barriers in the kernel) ----
    __syncthreads();
    #pragma unroll
    for (int hh = 0; hh < 8; ++hh) scr[wv*512 + hh*64 + lane] = accP[hh];
    #pragma unroll
    for (int k = 0; k < 4; ++k) scr[2048 + wv*256 + lane + 64*k] = accN4[k];
    if (!(lane & 1)) scr[3072 + wv*32 + g*8 + h] = s_part;
    __syncthreads();

    float* arow = g_agg + (size_t)row * AGG;
    // pair features: idx = h*64 + p, two per thread
    #pragma unroll
    for (int u = 0; u < 2; ++u) {
        int idx = 2*t + u;           // 0..511
        int hh = idx >> 6;
        float sv = 0.f;
        #pragma unroll
        for (int wg = 0; wg < 16; ++wg)
            sv += scr[3072 + (wg>>2)*32 + (wg&3)*8 + hh];
        float pv = scr[idx] + scr[512+idx] + scr[1024+idx] + scr[1536+idx];
        arow[NH + idx] = pv / sv;
    }
    // node features: c = t (h = c>>5)
    {
        int c = t;
        int hh = c >> 5;
        float sv = 0.f;
        #pragma unroll
        for (int wg = 0; wg < 16; ++wg)
            sv += scr[3072 + (wg>>2)*32 + (wg&3)*8 + hh];
        float nv = scr[2048+c] + scr[2048+256+c] + scr[2048+512+c] + scr[2048+768+c];
        arow[c] = nv / sv;
    }
}

// ---------------- K3: transition + LN + MLP + LN (4 rows / block) ----------------
__global__ __launch_bounds__(256) void k_mlp(const float* __restrict__ x,
    const float* __restrict__ Wt1, const float* __restrict__ bt1,
    const float* __restrict__ g1, const float* __restrict__ b1,
    const float* __restrict__ W2a, const float* __restrict__ b2a,
    const float* __restrict__ W2b, const float* __restrict__ b2b,
    const float* __restrict__ g2, const float* __restrict__ b2,
    float* __restrict__ out)
{
    __shared__ float aggL[4*AGG];    // 12KB
    __shared__ float featsL[4*132];
    __shared__ float h1L[4*132];
    int t = threadIdx.x;
    int tc = t & 127;
    int tr = t >> 7;    // 0/1
    int lane = t & 63, wv = t >> 6;
    int rowbase = blockIdx.x * 4;

    #pragma unroll
    for (int it = 0; it < 12; ++it) {
        int flat = it*256 + t;
        aggL[flat] = g_agg[(size_t)rowbase*AGG + flat];
    }
    __syncthreads();
    // GEMM1: feats_pre = x + agg @ Wt1 + bt1 (rows tr*2+r)
    float acc[2] = {0.f,0.f};
    for (int kk = 0; kk < AGG; ++kk) {
        float w = Wt1[kk*DN + tc];
        #pragma unroll
        for (int r = 0; r < 2; ++r)
            acc[r] = fmaf(aggL[(tr*2+r)*AGG + kk], w, acc[r]);
    }
    float bt = bt1[tc];
    #pragma unroll
    for (int r = 0; r < 2; ++r) {
        int row = tr*2 + r;
        featsL[row*132 + tc] = acc[r] + bt + x[(size_t)(rowbase+row)*DN + tc];
    }
    __syncthreads();
    // LN1: wave wv handles row wv
    {
        int row = wv;
        float v0 = featsL[row*132 + lane];
        float v1 = featsL[row*132 + 64 + lane];
        float s = v0 + v1, s2 = v0*v0 + v1*v1;
        #pragma unroll
        for (int o = 32; o > 0; o >>= 1) {
            s  += __shfl_xor(s,  o);
            s2 += __shfl_xor(s2, o);
        }
        float mean = s * (1.f/128.f);
        float var  = s2 * (1.f/128.f) - mean*mean;
        float rstd = rsqrtf(var + 1e-5f);
        featsL[row*132 + lane]      = (v0 - mean)*rstd*g1[lane]      + b1[lane];
        featsL[row*132 + 64 + lane] = (v1 - mean)*rstd*g1[64+lane]   + b1[64+lane];
    }
    __syncthreads();
    // GEMM2 + relu
    float acc2[2] = {0.f,0.f};
    for (int kk = 0; kk < DN; ++kk) {
        float w = W2a[kk*DN + tc];
        #pragma unroll
        for (int r = 0; r < 2; ++r)
            acc2[r] = fmaf(featsL[(tr*2+r)*132 + kk], w, acc2[r]);
    }
    float ba = b2a[tc];
    #pragma unroll
    for (int r = 0; r < 2; ++r)
        h1L[(tr*2+r)*132 + tc] = fmaxf(acc2[r] + ba, 0.f);
    __syncthreads();
    // GEMM3 + residual
    float acc3[2] = {0.f,0.f};
    for (int kk = 0; kk < DN; ++kk) {
        float w = W2b[kk*DN + tc];
        #pragma unroll
        for (int r = 0; r < 2; ++r)
            acc3[r] = fmaf(h1L[(tr*2+r)*132 + kk], w, acc3[r]);
    }
    float bb = b2b[tc];
    #pragma unroll
    for (int r = 0; r < 2; ++r) {
        int row = tr*2 + r;
        featsL[row*132 + tc] = featsL[row*132 + tc] + acc3[r] + bb;
    }
    __syncthreads();
    // LN2 -> out
    {
        int row = wv;
        float v0 = featsL[row*132 + lane];
        float v1 = featsL[row*132 + 64 + lane];
        float s = v0 + v1, s2 = v0*v0 + v1*v1;
        #pragma unroll
        for (int o = 32; o > 0; o >>= 1) {
            s  += __shfl_xor(s,  o);
            s2 += __shfl_xor(s2, o);
        }
        float mean = s * (1.f/128.f);
        float var  = s2 * (1.f/128.f) - mean*mean;
        float rstd = rsqrtf(var + 1e-5f);
        out[(size_t)(rowbase+row)*DN + lane]      = (v0 - mean)*rstd*g2[lane]    + b2[lane];
        out[(size_t)(rowbase+row)*DN + 64 + lane] = (v1 - mean)*rstd*g2[64+lane] + b2[64+lane];
    }
}

extern "C" void kernel_launch(void* const* d_in, const int* in_sizes, int n_in,
                              void* d_out, int out_size, void* d_ws, size_t ws_size,
                              hipStream_t stream) {
    const float* x   = (const float*)d_in[0];
    const float* z   = (const float*)d_in[1];
    const float* Wq  = (const float*)d_in[2];
    const float* Wk  = (const float*)d_in[3];
    const float* Wv  = (const float*)d_in[4];
    const float* Wp  = (const float*)d_in[5];
    const float* Wt1 = (const float*)d_in[6];
    const float* bt1 = (const float*)d_in[7];
    const float* g1  = (const float*)d_in[8];
    const float* b1  = (const float*)d_in[9];
    const float* W2a = (const float*)d_in[10];
    const float* b2a = (const float*)d_in[11];
    const float* W2b = (const float*)d_in[12];
    const float* b2b = (const float*)d_in[13];
    const float* g2  = (const float*)d_in[14];
    const float* b2  = (const float*)d_in[15];
    float* out = (float*)d_out;

    k_qkv<<<NB*L/4, 256, 0, stream>>>(x, Wq, Wk, Wv);
    k_qk<<<NB*H*(L/16), 256, 0, stream>>>();
    k_attn<<<NB*L, 256, 0, stream>>>(z, Wp);
    k_mlp<<<NB*L/4, 256, 0, stream>>>(x, Wt1, bt1, g1, b1,
                                      W2a, b2a, W2b, b2b, g2, b2, out);
}

// Round 19
// 190.347 us; speedup vs baseline: 1.2569x; 1.2569x over previous
//
#include <hip/hip_runtime.h>
#include <math.h>

#define NB 4
#define L 512
#define DN 128
#define DP 64
#define H 8
#define HD 32
#define NH (H*HD)        // 256
#define AGG (NH + H*DP)  // 768
#define JC 64
#define NCH (L/JC)       // 8

// static device scratch
__device__ float g_qT[(size_t)NB*H*L*HD];  // [n][h][i][d], q*0.125
__device__ float g_kT[(size_t)NB*H*L*HD];  // [n][h][j][d]
__device__ float g_v[NB*L*NH];             // [n][j][h*32+d]
__device__ float g_agg[NB*L*AGG];
__device__ float g_nl[(size_t)NB*H*L*L];   // 33.5MB [n][h][i][j]

// ---------------- K1: QKV projection (4 rows / block) ----------------
__global__ __launch_bounds__(256) void k_qkv(const float* __restrict__ x,
    const float* __restrict__ Wq, const float* __restrict__ Wk,
    const float* __restrict__ Wv)
{
    __shared__ float xs[4*DN];
    int t = threadIdx.x;
    int rowbase = blockIdx.x * 4;
    #pragma unroll
    for (int it = 0; it < 2; ++it) {
        int flat = it*256 + t;
        xs[flat] = x[(size_t)rowbase*DN + flat];
    }
    __syncthreads();
    float aq[4], ak[4], av[4];
    #pragma unroll
    for (int r = 0; r < 4; ++r) { aq[r]=0.f; ak[r]=0.f; av[r]=0.f; }
    for (int d = 0; d < DN; ++d) {
        float wq = Wq[d*NH + t];
        float wk = Wk[d*NH + t];
        float wv = Wv[d*NH + t];
        #pragma unroll
        for (int r = 0; r < 4; ++r) {
            float xv = xs[r*DN + d];
            aq[r] = fmaf(xv, wq, aq[r]);
            ak[r] = fmaf(xv, wk, ak[r]);
            av[r] = fmaf(xv, wv, av[r]);
        }
    }
    int n2 = rowbase >> 9;
    int i0 = rowbase & 511;
    int h = t >> 5, d = t & 31;
    #pragma unroll
    for (int r = 0; r < 4; ++r) {
        // q/k transposed per-head rows ([n][h][i][d]); fold (1/sqrt32)*sqrt(.5)=0.125 into q
        size_t base = ((size_t)(n2*H + h)*L + i0 + r)*HD + d;
        g_qT[base] = aq[r] * 0.125f;
        g_kT[base] = ak[r];
        g_v[(size_t)(rowbase+r)*NH + t] = av[r];
    }
}

// ---------------- K1.5: node logits GEMM: nl[n,h,i,j] = q[i]·k[j] ----------------
__global__ __launch_bounds__(256) void k_qk()
{
    __shared__ __align__(16) float qs[16*36];
    int t = threadIdx.x;
    int bid = blockIdx.x;            // n*256 + h*32 + itile
    int n = bid >> 8;
    int h = (bid >> 5) & 7;
    int i0 = (bid & 31) << 4;
    const float* qTb = g_qT + (size_t)((n*H + h)*L + i0)*HD;
    if (t < 128) {
        int row = t >> 3, c4 = (t & 7) << 2;
        float4 qv = *(const float4*)(qTb + row*HD + c4);
        *(float4*)&qs[row*36 + c4] = qv;
    }
    __syncthreads();
    const float* kTb = g_kT + (size_t)(n*H + h)*L*HD;
    for (int jc = 0; jc < L; jc += 256) {
        int j = jc + t;
        float4 kr[8];
        const float4* kb = (const float4*)(kTb + (size_t)j*HD);
        #pragma unroll
        for (int c4 = 0; c4 < 8; ++c4) kr[c4] = kb[c4];
        float* outb = g_nl + (size_t)((n*H + h)*L + i0)*L + j;
        #pragma unroll 4
        for (int i = 0; i < 16; ++i) {
            float a0 = 0.f, a1 = 0.f;
            #pragma unroll
            for (int c4 = 0; c4 < 8; c4 += 2) {
                float4 q0 = *(const float4*)&qs[i*36 + c4*4];
                float4 q1 = *(const float4*)&qs[i*36 + c4*4 + 4];
                a0 = fmaf(q0.x, kr[c4].x,   fmaf(q0.y, kr[c4].y,   a0));
                a0 = fmaf(q0.z, kr[c4].z,   fmaf(q0.w, kr[c4].w,   a0));
                a1 = fmaf(q1.x, kr[c4+1].x, fmaf(q1.y, kr[c4+1].y, a1));
                a1 = fmaf(q1.z, kr[c4+1].z, fmaf(q1.w, kr[c4+1].w, a1));
            }
            outb[(size_t)i*L] = a0 + a1;
        }
    }
}

// ---------------- K2: wave-private flash attention, zero loop barriers --------
// Wave w owns the 16 j-rows it stages. Logits from staging REGISTERS (Wp in 32
// regs/thread), head-thinning butterfly reduce. Max-free exp. Phase D: wave
// aggregates its own 16 j across all 8 heads. One cross-wave combine at end.
// (r15/r17 configuration: best verified, replay-stable.)

#define LOGITS(BUF, NLARR)                                                     \
  { _Pragma("unroll")                                                          \
    for (int it2 = 0; it2 < 4; ++it2) {                                        \
      float4 zv = zR[it2];                                                     \
      float p0 = fmaf(zv.x,wA0.x, fmaf(zv.y,wA1.x, fmaf(zv.z,wA2.x, zv.w*wA3.x))); \
      float p1 = fmaf(zv.x,wA0.y, fmaf(zv.y,wA1.y, fmaf(zv.z,wA2.y, zv.w*wA3.y))); \
      float p2 = fmaf(zv.x,wA0.z, fmaf(zv.y,wA1.z, fmaf(zv.z,wA2.z, zv.w*wA3.z))); \
      float p3 = fmaf(zv.x,wA0.w, fmaf(zv.y,wA1.w, fmaf(zv.z,wA2.w, zv.w*wA3.w))); \
      float p4 = fmaf(zv.x,wB0.x, fmaf(zv.y,wB1.x, fmaf(zv.z,wB2.x, zv.w*wB3.x))); \
      float p5 = fmaf(zv.x,wB0.y, fmaf(zv.y,wB1.y, fmaf(zv.z,wB2.y, zv.w*wB3.y))); \
      float p6 = fmaf(zv.x,wB0.z, fmaf(zv.y,wB1.z, fmaf(zv.z,wB2.z, zv.w*wB3.z))); \
      float p7 = fmaf(zv.x,wB0.w, fmaf(zv.y,wB1.w, fmaf(zv.z,wB2.w, zv.w*wB3.w))); \
      bool s8 = (lane & 8) != 0;                                               \
      float k0 = s8 ? p4 : p0, d0 = s8 ? p0 : p4;                              \
      float k1 = s8 ? p5 : p1, d1 = s8 ? p1 : p5;                              \
      float k2 = s8 ? p6 : p2, d2 = s8 ? p2 : p6;                              \
      float k3 = s8 ? p7 : p3, d3 = s8 ? p3 : p7;                              \
      k0 += __shfl_xor(d0, 8); k1 += __shfl_xor(d1, 8);                        \
      k2 += __shfl_xor(d2, 8); k3 += __shfl_xor(d3, 8);                        \
      bool s4 = (lane & 4) != 0;                                               \
      float m0 = s4 ? k2 : k0, e0 = s4 ? k0 : k2;                              \
      float m1 = s4 ? k3 : k1, e1 = s4 ? k1 : k3;                              \
      m0 += __shfl_xor(e0, 4); m1 += __shfl_xor(e1, 4);                        \
      bool s2b = (lane & 2) != 0;                                              \
      float r0 = s2b ? m1 : m0, r1 = s2b ? m0 : m1;                            \
      r0 += __shfl_xor(r1, 2);                                                 \
      r0 += __shfl_xor(r0, 1);                                                 \
      float e = __expf(r0 + NLARR[it2]);                                       \
      if (!(lane & 1)) { s_part += e; lcw[BUF][wv][it2*4 + g][h] = e; }        \
    } }

#define STAGE(BUF)                                                             \
  { _Pragma("unroll")                                                          \
    for (int it2 = 0; it2 < 4; ++it2) {                                        \
      int f4 = it2*256 + t, jj = f4 >> 4, p4i = (f4 & 15) << 2;                \
      float* d = &zc[BUF][jj*65 + p4i];                                        \
      d[0]=zR[it2].x; d[1]=zR[it2].y; d[2]=zR[it2].z; d[3]=zR[it2].w;          \
    } }

#define ZLOAD(cc)                                                              \
  { const float4* sp = (const float4*)(zrow + (size_t)(cc)*JC*DP);             \
    zR[0]=sp[t]; zR[1]=sp[256+t]; zR[2]=sp[512+t]; zR[3]=sp[768+t]; }

#define NLOAD(cc, ARR)                                                         \
  { _Pragma("unroll")                                                          \
    for (int q2 = 0; q2 < 4; ++q2) ARR[q2] = nlb[(cc)*64 + q2*16]; }

#define PHASED(cc)                                                             \
  { const float* zcc = zc[(cc)&1];                                             \
    const float* vb = g_v + (size_t)(n*L + (size_t)(cc)*JC)*NH + lane;         \
    _Pragma("unroll 4")                                                        \
    for (int jl = 0; jl < 16; ++jl) {                                          \
      int j = ((jl>>2)<<4) + 4*wv + (jl&3);                                    \
      float4 aL = *(const float4*)&lcw[(cc)&1][wv][jl][0];                     \
      float4 aH = *(const float4*)&lcw[(cc)&1][wv][jl][4];                     \
      float zv = zcc[j*65 + lane];                                             \
      const float* vr = vb + (size_t)j*NH;                                     \
      float v0 = vr[0], v1 = vr[64], v2 = vr[128], v3 = vr[192];               \
      accP[0] = fmaf(aL.x, zv, accP[0]);                                       \
      accP[1] = fmaf(aL.y, zv, accP[1]);                                       \
      accP[2] = fmaf(aL.z, zv, accP[2]);                                       \
      accP[3] = fmaf(aL.w, zv, accP[3]);                                       \
      accP[4] = fmaf(aH.x, zv, accP[4]);                                       \
      accP[5] = fmaf(aH.y, zv, accP[5]);                                       \
      accP[6] = fmaf(aH.z, zv, accP[6]);                                       \
      accP[7] = fmaf(aH.w, zv, accP[7]);                                       \
      float a0 = hi ? aL.y : aL.x;                                             \
      float a1 = hi ? aL.w : aL.z;                                             \
      float a2 = hi ? aH.y : aH.x;                                             \
      float a3 = hi ? aH.w : aH.z;                                             \
      accN4[0] = fmaf(a0, v0, accN4[0]);                                       \
      accN4[1] = fmaf(a1, v1, accN4[1]);                                       \
      accN4[2] = fmaf(a2, v2, accN4[2]);                                       \
      accN4[3] = fmaf(a3, v3, accN4[3]);                                       \
    } }

#define AITER(c, USE, LOADINTO)                                                \
  { if ((c)+1 < NCH) { LOGITS(((c)+1)&1, USE) STAGE(((c)+1)&1) }               \
    if ((c)+2 < NCH) { ZLOAD((c)+2) NLOAD((c)+2, LOADINTO) }                   \
    PHASED(c) }

__global__ __launch_bounds__(256) void k_attn(const float* __restrict__ z,
    const float* __restrict__ Wp)
{
    __shared__ __align__(16) float zc[2][JC*65];     // 33.3 KB, rows wave-private
    __shared__ __align__(16) float lcw[2][4][16][8]; // 4 KB alpha, wave-private

    int t = threadIdx.x;
    int lane = t & 63;
    int wv = t >> 6;
    int row = blockIdx.x;            // n*L + i
    int n = row >> 9;
    int i = row & 511;
    const float* zrow = z + (size_t)row * (L*DP);

    int g = lane >> 4;               // j-group within wave (0..3)
    int b = lane & 15;               // position in group = p-slice index
    int h = (lane & 14) >> 1;        // head this thread reduces to
    bool hi = (lane >= 32);

    // Wp slice in registers: rows p=4b..4b+3, heads 0-3 (wA*) and 4-7 (wB*)
    const float SQ = 0.70710678118654752f;
    float4 wA0, wA1, wA2, wA3, wB0, wB1, wB2, wB3;
    {
        const float4* w0 = (const float4*)(Wp + (4*b + 0)*H);
        const float4* w1 = (const float4*)(Wp + (4*b + 1)*H);
        const float4* w2 = (const float4*)(Wp + (4*b + 2)*H);
        const float4* w3 = (const float4*)(Wp + (4*b + 3)*H);
        wA0 = w0[0]; wB0 = w0[1]; wA1 = w1[0]; wB1 = w1[1];
        wA2 = w2[0]; wB2 = w2[1]; wA3 = w3[0]; wB3 = w3[1];
        wA0.x*=SQ; wA0.y*=SQ; wA0.z*=SQ; wA0.w*=SQ;
        wA1.x*=SQ; wA1.y*=SQ; wA1.z*=SQ; wA1.w*=SQ;
        wA2.x*=SQ; wA2.y*=SQ; wA2.z*=SQ; wA2.w*=SQ;
        wA3.x*=SQ; wA3.y*=SQ; wA3.z*=SQ; wA3.w*=SQ;
        wB0.x*=SQ; wB0.y*=SQ; wB0.z*=SQ; wB0.w*=SQ;
        wB1.x*=SQ; wB1.y*=SQ; wB1.z*=SQ; wB1.w*=SQ;
        wB2.x*=SQ; wB2.y*=SQ; wB2.z*=SQ; wB2.w*=SQ;
        wB3.x*=SQ; wB3.y*=SQ; wB3.z*=SQ; wB3.w*=SQ;
    }

    // nl pointer for (head h, query i), j-offset 4wv+g; nlb[c*64 + 16*it2]
    const float* nlb = g_nl + ((size_t)((n*H + h)*L + i))*L + 4*wv + g;

    float accP[8] = {0.f,0.f,0.f,0.f,0.f,0.f,0.f,0.f};
    float accN4[4] = {0.f,0.f,0.f,0.f};
    float s_part = 0.f;
    float4 zR[4];
    float nlC[4], nlN[4];

    // prologue: chunk0 regs -> logits(0) -> stage buf0; zR <- chunk1
    ZLOAD(0) NLOAD(0, nlC)
    LOGITS(0, nlC)
    STAGE(0)
    ZLOAD(1) NLOAD(1, nlN)

    AITER(0, nlN, nlC)
    AITER(1, nlC, nlN)
    AITER(2, nlN, nlC)
    AITER(3, nlC, nlN)
    AITER(4, nlN, nlC)
    AITER(5, nlC, nlN)
    AITER(6, nlN, nlC)
    AITER(7, nlC, nlN)

    // ---- cross-wave combine (only barriers in the kernel) ----
    __syncthreads();
    float* scr = &zc[0][0];          // 3200 floats scratch (zc is done)
    #pragma unroll
    for (int hh = 0; hh < 8; ++hh) scr[wv*512 + hh*64 + lane] = accP[hh];
    #pragma unroll
    for (int k = 0; k < 4; ++k) scr[2048 + wv*256 + lane + 64*k] = accN4[k];
    if (!(lane & 1)) scr[3072 + wv*32 + g*8 + h] = s_part;
    __syncthreads();

    float* arow = g_agg + (size_t)row * AGG;
    // pair features: idx = h*64 + p, two per thread
    #pragma unroll
    for (int u = 0; u < 2; ++u) {
        int idx = 2*t + u;           // 0..511
        int hh = idx >> 6;
        float sv = 0.f;
        #pragma unroll
        for (int wg = 0; wg < 16; ++wg)
            sv += scr[3072 + (wg>>2)*32 + (wg&3)*8 + hh];
        float pv = scr[idx] + scr[512+idx] + scr[1024+idx] + scr[1536+idx];
        arow[NH + idx] = pv / sv;
    }
    // node features: c = t (h = c>>5)
    {
        int c = t;
        int hh = c >> 5;
        float sv = 0.f;
        #pragma unroll
        for (int wg = 0; wg < 16; ++wg)
            sv += scr[3072 + (wg>>2)*32 + (wg&3)*8 + hh];
        float nv = scr[2048+c] + scr[2048+256+c] + scr[2048+512+c] + scr[2048+768+c];
        arow[c] = nv / sv;
    }
}

// ---------------- K3: transition + LN + MLP + LN (4 rows / block) ----------------
__global__ __launch_bounds__(256) void k_mlp(const float* __restrict__ x,
    const float* __restrict__ Wt1, const float* __restrict__ bt1,
    const float* __restrict__ g1, const float* __restrict__ b1,
    const float* __restrict__ W2a, const float* __restrict__ b2a,
    const float* __restrict__ W2b, const float* __restrict__ b2b,
    const float* __restrict__ g2, const float* __restrict__ b2,
    float* __restrict__ out)
{
    __shared__ float aggL[4*AGG];    // 12KB
    __shared__ float featsL[4*132];
    __shared__ float h1L[4*132];
    int t = threadIdx.x;
    int tc = t & 127;
    int tr = t >> 7;    // 0/1
    int lane = t & 63, wv = t >> 6;
    int rowbase = blockIdx.x * 4;

    #pragma unroll
    for (int it = 0; it < 12; ++it) {
        int flat = it*256 + t;
        aggL[flat] = g_agg[(size_t)rowbase*AGG + flat];
    }
    __syncthreads();
    // GEMM1: feats_pre = x + agg @ Wt1 + bt1 (rows tr*2+r)
    float acc[2] = {0.f,0.f};
    for (int kk = 0; kk < AGG; ++kk) {
        float w = Wt1[kk*DN + tc];
        #pragma unroll
        for (int r = 0; r < 2; ++r)
            acc[r] = fmaf(aggL[(tr*2+r)*AGG + kk], w, acc[r]);
    }
    float bt = bt1[tc];
    #pragma unroll
    for (int r = 0; r < 2; ++r) {
        int row = tr*2 + r;
        featsL[row*132 + tc] = acc[r] + bt + x[(size_t)(rowbase+row)*DN + tc];
    }
    __syncthreads();
    // LN1: wave wv handles row wv
    {
        int row = wv;
        float v0 = featsL[row*132 + lane];
        float v1 = featsL[row*132 + 64 + lane];
        float s = v0 + v1, s2 = v0*v0 + v1*v1;
        #pragma unroll
        for (int o = 32; o > 0; o >>= 1) {
            s  += __shfl_xor(s,  o);
            s2 += __shfl_xor(s2, o);
        }
        float mean = s * (1.f/128.f);
        float var  = s2 * (1.f/128.f) - mean*mean;
        float rstd = rsqrtf(var + 1e-5f);
        featsL[row*132 + lane]      = (v0 - mean)*rstd*g1[lane]      + b1[lane];
        featsL[row*132 + 64 + lane] = (v1 - mean)*rstd*g1[64+lane]   + b1[64+lane];
    }
    __syncthreads();
    // GEMM2 + relu
    float acc2[2] = {0.f,0.f};
    for (int kk = 0; kk < DN; ++kk) {
        float w = W2a[kk*DN + tc];
        #pragma unroll
        for (int r = 0; r < 2; ++r)
            acc2[r] = fmaf(featsL[(tr*2+r)*132 + kk], w, acc2[r]);
    }
    float ba = b2a[tc];
    #pragma unroll
    for (int r = 0; r < 2; ++r)
        h1L[(tr*2+r)*132 + tc] = fmaxf(acc2[r] + ba, 0.f);
    __syncthreads();
    // GEMM3 + residual
    float acc3[2] = {0.f,0.f};
    for (int kk = 0; kk < DN; ++kk) {
        float w = W2b[kk*DN + tc];
        #pragma unroll
        for (int r = 0; r < 2; ++r)
            acc3[r] = fmaf(h1L[(tr*2+r)*132 + kk], w, acc3[r]);
    }
    float bb = b2b[tc];
    #pragma unroll
    for (int r = 0; r < 2; ++r) {
        int row = tr*2 + r;
        featsL[row*132 + tc] = featsL[row*132 + tc] + acc3[r] + bb;
    }
    __syncthreads();
    // LN2 -> out
    {
        int row = wv;
        float v0 = featsL[row*132 + lane];
        float v1 = featsL[row*132 + 64 + lane];
        float s = v0 + v1, s2 = v0*v0 + v1*v1;
        #pragma unroll
        for (int o = 32; o > 0; o >>= 1) {
            s  += __shfl_xor(s,  o);
            s2 += __shfl_xor(s2, o);
        }
        float mean = s * (1.f/128.f);
        float var  = s2 * (1.f/128.f) - mean*mean;
        float rstd = rsqrtf(var + 1e-5f);
        out[(size_t)(rowbase+row)*DN + lane]      = (v0 - mean)*rstd*g2[lane]    + b2[lane];
        out[(size_t)(rowbase+row)*DN + 64 + lane] = (v1 - mean)*rstd*g2[64+lane] + b2[64+lane];
    }
}

extern "C" void kernel_launch(void* const* d_in, const int* in_sizes, int n_in,
                              void* d_out, int out_size, void* d_ws, size_t ws_size,
                              hipStream_t stream) {
    const float* x   = (const float*)d_in[0];
    const float* z   = (const float*)d_in[1];
    const float* Wq  = (const float*)d_in[2];
    const float* Wk  = (const float*)d_in[3];
    const float* Wv  = (const float*)d_in[4];
    const float* Wp  = (const float*)d_in[5];
    const float* Wt1 = (const float*)d_in[6];
    const float* bt1 = (const float*)d_in[7];
    const float* g1  = (const float*)d_in[8];
    const float* b1  = (const float*)d_in[9];
    const float* W2a = (const float*)d_in[10];
    const float* b2a = (const float*)d_in[11];
    const float* W2b = (const float*)d_in[12];
    const float* b2b = (const float*)d_in[13];
    const float* g2  = (const float*)d_in[14];
    const float* b2  = (const float*)d_in[15];
    float* out = (float*)d_out;

    k_qkv<<<NB*L/4, 256, 0, stream>>>(x, Wq, Wk, Wv);
    k_qk<<<NB*H*(L/16), 256, 0, stream>>>();
    k_attn<<<NB*L, 256, 0, stream>>>(z, Wp);
    k_mlp<<<NB*L/4, 256, 0, stream>>>(x, Wt1, bt1, g1, b1,
                                      W2a, b2a, W2b, b2b, g2, b2, out);
}